// Round 17
// baseline (137.464 us; speedup 1.0000x reference)
//
#include <hip/hip_runtime.h>

#define N_NODES 100000
#define D 64
#define NTILES 3125       // 32-node output tiles for tile_g1
#define NBUCK 391         // 256-node buckets: dst>>8
#define NBLK_A 256        // blocks in count/place passes
#define GCNT_N (NBUCK * NBLK_A)            // 100096
#define NTILE_T (N_NODES / 32)             // transform tiles
#define TROW 72           // staged row stride in bf16 elems (144B)
#define TBLK 512          // transform blocks inside fused kernel

typedef __attribute__((ext_vector_type(8))) short short8;
typedef __attribute__((ext_vector_type(16))) float f32x16;
union Pack8 { uint4 u; short8 s; };

__device__ __forceinline__ unsigned f2bf(float f) {  // RNE float->bf16 bits
  unsigned u = __float_as_uint(f);
  return (u + 0x7fffu + ((u >> 16) & 1u)) >> 16;
}
#define BF_LO(u) __uint_as_float(((unsigned)(u)) << 16)
#define BF_HI(u) __uint_as_float(((unsigned)(u)) & 0xffff0000u)

// Packed edge record: bits 31..24 = dst&255 (bucket-local), bits 23..0 = src.

// ---------- passA: per-block histogram + atomic range reservation ----------
// goff[b*NBLK_A+blk] = exclusive offset of this block's edges within bucket b.
// Replaces the 3-kernel scan chain (order within a bucket becomes
// timing-dependent -> benign f32 sum-order ulp noise, same class as the
// existing LDS-cursor placement).
__global__ __launch_bounds__(256) void passA_count(const int* __restrict__ dst,
                                                   int* __restrict__ goff,
                                                   int* __restrict__ btot,
                                                   int nE, int ec) {
  __shared__ int cnt[NBUCK];
  int t = threadIdx.x, blk = blockIdx.x;
  for (int i = t; i < NBUCK; i += 256) cnt[i] = 0;
  __syncthreads();
  int e0 = blk * ec, e1 = min(e0 + ec, nE);
  for (int e = e0 + t; e < e1; e += 256) atomicAdd(&cnt[dst[e] >> 8], 1);
  __syncthreads();
  for (int b = t; b < NBUCK; b += 256)
    goff[b * NBLK_A + blk] = atomicAdd(&btot[b], cnt[b]);
}

// ---------- passC (blocks 0..NBLK_A-1) + prep (block NBLK_A) fused ----------
// Each placing block scans btot in LDS (redundant-parallel) to get bucket
// bases; block 0 persists bstart[] for passD / bucket_g2.
__global__ __launch_bounds__(256) void passC_prep(
    const int* __restrict__ src, const int* __restrict__ dst,
    const int* __restrict__ goff, const int* __restrict__ btot,
    int* __restrict__ bstart, unsigned* __restrict__ pairs4, int nE, int ec,
    const float* __restrict__ Wc, const float* __restrict__ Wl2,
    const float* __restrict__ Wr2, const float* __restrict__ bl2,
    const float* __restrict__ bc, const float* __restrict__ Wl1,
    const float* __restrict__ Wr1, float* __restrict__ A2,
    float* __restrict__ B2, float* __restrict__ bfv,
    unsigned short* __restrict__ wcat) {
  __shared__ int cur[NBUCK];
  __shared__ int sa[512], sb[512];
  int t = threadIdx.x, blk = blockIdx.x;
  if (blk < NBLK_A) {
    for (int i = t; i < 512; i += 256) sa[i] = (i < NBUCK) ? btot[i] : 0;
    __syncthreads();
    int* A = sa;
    int* B = sb;
    for (int off = 1; off < 512; off <<= 1) {
      for (int i = t; i < 512; i += 256)
        B[i] = A[i] + ((i >= off) ? A[i - off] : 0);
      __syncthreads();
      int* tmp = A; A = B; B = tmp;
    }
    // A = inclusive scan of btot; exclusive base[b] = (b? A[b-1] : 0)
    for (int b = t; b < NBUCK; b += 256) {
      int base = (b == 0) ? 0 : A[b - 1];
      cur[b] = base + goff[b * NBLK_A + blk];
      if (blk == 0) bstart[b] = base;
    }
    if (blk == 0 && t == 0) bstart[NBUCK] = A[NBUCK - 1];  // == nE
    __syncthreads();
    int e0 = blk * ec, e1 = min(e0 + ec, nE);
    for (int e = e0 + t; e < e1; e += 256) {
      int d = dst[e];
      int p = atomicAdd(&cur[d >> 8], 1);
      pairs4[p] = ((unsigned)(d & 255) << 24) | (unsigned)src[e];
    }
  } else {
    for (int i = t; i < 8192; i += 256)
      wcat[i] = (unsigned short)f2bf((i < 4096) ? Wl1[i] : Wr1[i - 4096]);
    if (t < 128) {
      int c = t >> 6, k = t & 63;
      float sa2 = 0.f, sb2 = 0.f;
      for (int j = 0; j < 64; ++j) {
        float w = Wc[c * 64 + j];
        sa2 = fmaf(w, Wl2[j * 64 + k], sa2);
        sb2 = fmaf(w, Wr2[j * 64 + k], sb2);
      }
      A2[c * 64 + k] = sa2;
      B2[c * 64 + k] = sb2;
    }
    if (t < 2) {
      float s = bc[t];
      for (int j = 0; j < 64; ++j) s = fmaf(Wc[t * 64 + j], bl2[j], s);
      bfv[t] = s;
    }
  }
}

// ---------- fused: tile-sort passD (blocks 0..NBUCK-1) + transform ----------
__global__ __launch_bounds__(256) void passD_transform(
    const unsigned* __restrict__ pairs4, const int* __restrict__ bstart,
    int* __restrict__ tstart, unsigned* __restrict__ srt4, int nE,
    const float* __restrict__ x, const unsigned short* __restrict__ wcat,
    const float* __restrict__ bl, unsigned short* __restrict__ t1,
    unsigned short* __restrict__ r1b) {
  __shared__ int h8[8 * 16];
  __shared__ int ex8[9];
  __shared__ int cur8[8];
  int t = threadIdx.x;
  if (blockIdx.x < NBUCK) {
    int b = blockIdx.x;
    int base = bstart[b];
    int end = bstart[b + 1];
    if (t < 128) h8[t] = 0;
    __syncthreads();
    for (int p = base + t; p < end; p += 256)
      atomicAdd(&h8[((pairs4[p] >> 29) & 7) * 16 + (t & 15)], 1);
    __syncthreads();
    if (t == 0) {
      int run = base;
      for (int bin = 0; bin < 8; ++bin) {
        ex8[bin] = run;
        int s = 0;
        for (int i = 0; i < 16; ++i) s += h8[bin * 16 + i];
        run += s;
      }
      ex8[8] = run;
    }
    __syncthreads();
    if (t < 8) {
      cur8[t] = ex8[t];
      tstart[b * 8 + t] = ex8[t];
    }
    if (b == NBUCK - 1 && t == 0) tstart[NBUCK * 8] = nE;
    __syncthreads();
    for (int p = base + t; p < end; p += 256) {
      unsigned pk = pairs4[p];
      int slot = atomicAdd(&cur8[(pk >> 29) & 7], 1);
      srt4[slot] = pk;
    }
  } else {
    int lane = t & 63;
    int l31 = lane & 31, hi = lane >> 5;

    short8 af[4][4];
#pragma unroll
    for (int jt = 0; jt < 4; ++jt)
#pragma unroll
      for (int kk = 0; kk < 4; ++kk)
        af[jt][kk] =
            *(const short8*)(wcat + (jt * 32 + l31) * 64 + kk * 16 + 8 * hi);

    const f32x16 Z = {0.f, 0.f, 0.f, 0.f, 0.f, 0.f, 0.f, 0.f,
                      0.f, 0.f, 0.f, 0.f, 0.f, 0.f, 0.f, 0.f};
    const float4* x4 = (const float4*)x;

    int gw = ((blockIdx.x - NBUCK) * 256 + t) >> 6;
    int nW = (TBLK * 256) >> 6;

    for (int tile = gw; tile < NTILE_T; tile += nW) {
      int node = tile * 32 + l31;
      f32x16 acc[4] = {Z, Z, Z, Z};
#pragma unroll
      for (int kk = 0; kk < 4; ++kk) {
        float4 fa = x4[(size_t)node * 16 + kk * 4 + 2 * hi];
        float4 fb = x4[(size_t)node * 16 + kk * 4 + 2 * hi + 1];
        Pack8 pk;
        pk.u.x = f2bf(fa.x) | (f2bf(fa.y) << 16);
        pk.u.y = f2bf(fa.z) | (f2bf(fa.w) << 16);
        pk.u.z = f2bf(fb.x) | (f2bf(fb.y) << 16);
        pk.u.w = f2bf(fb.z) | (f2bf(fb.w) << 16);
        acc[0] = __builtin_amdgcn_mfma_f32_32x32x16_bf16(af[0][kk], pk.s, acc[0], 0, 0, 0);
        acc[1] = __builtin_amdgcn_mfma_f32_32x32x16_bf16(af[1][kk], pk.s, acc[1], 0, 0, 0);
        acc[2] = __builtin_amdgcn_mfma_f32_32x32x16_bf16(af[2][kk], pk.s, acc[2], 0, 0, 0);
        acc[3] = __builtin_amdgcn_mfma_f32_32x32x16_bf16(af[3][kk], pk.s, acc[3], 0, 0, 0);
      }
#pragma unroll
      for (int jt = 0; jt < 2; ++jt)
#pragma unroll
        for (int rg = 0; rg < 4; ++rg) {
          int j0 = jt * 32 + 8 * rg + 4 * hi;
          uint2 p;
          p.x = f2bf(acc[jt][4 * rg + 0]) | (f2bf(acc[jt][4 * rg + 1]) << 16);
          p.y = f2bf(acc[jt][4 * rg + 2]) | (f2bf(acc[jt][4 * rg + 3]) << 16);
          *(uint2*)(t1 + (size_t)node * 64 + j0) = p;
        }
#pragma unroll
      for (int jt = 2; jt < 4; ++jt)
#pragma unroll
        for (int rg = 0; rg < 4; ++rg) {
          int j0 = (jt - 2) * 32 + 8 * rg + 4 * hi;
          float4 bv = ((const float4*)bl)[j0 >> 2];
          uint2 p;
          p.x = f2bf(acc[jt][4 * rg + 0] + bv.x) |
                (f2bf(acc[jt][4 * rg + 1] + bv.y) << 16);
          p.y = f2bf(acc[jt][4 * rg + 2] + bv.z) |
                (f2bf(acc[jt][4 * rg + 3] + bv.w) << 16);
          *(uint2*)(r1b + (size_t)node * 64 + j0) = p;
        }
    }
  }
}

// ---------- tile_g1: MFMA indicator-gather, 4 waves per tile ----------
__global__ __launch_bounds__(256) void tile_g1(
    const unsigned* __restrict__ srt4, const int* __restrict__ tstart,
    const unsigned short* __restrict__ t1,
    const unsigned short* __restrict__ r1b, const float* __restrict__ A2,
    const float* __restrict__ B2, float2* __restrict__ g2,
    float2* __restrict__ s2, int nE) {
  __shared__ float pAB[4][64];
  __shared__ unsigned short stg[4][2][16 * TROW];
  __shared__ int ideg[4][64];
  int t = threadIdx.x, lane = t & 63, w = t >> 6;
  pAB[t >> 6][t & 63] = (t < 128) ? A2[t] : B2[t - 128];
  __syncthreads();

  int tile = blockIdx.x;
  int base = tstart[tile];
  int end = tstart[tile + 1];
  int l31 = lane & 31, hi = lane >> 5;
  int o = lane >> 3, j8 = lane & 7;
  unsigned short* stA = &stg[w][0][0];
  unsigned short* stB = &stg[w][1][0];

  int ngAll = (end > base) ? ((end - base + 15) >> 4) : 0;
  int gper = (ngAll + 3) >> 2;
  int wbase = base + min(w * gper, ngAll) * 16;
  int wend = min(base + min((w + 1) * gper, ngAll) * 16, end);

  const f32x16 Z = {0.f, 0.f, 0.f, 0.f, 0.f, 0.f, 0.f, 0.f,
                    0.f, 0.f, 0.f, 0.f, 0.f, 0.f, 0.f, 0.f};
  f32x16 acc0 = Z, acc1 = Z;
  int degc = 0;
  int ng = (wend > wbase) ? ((wend - wbase + 15) >> 4) : 0;

  unsigned pkA = 0u, pkB = 0u;
  int cntA = 0, cntB = 0;
  uint4 vA0 = make_uint4(0, 0, 0, 0), vA1 = vA0, vB0 = vA0, vB1 = vA0;
  if (ng > 0) {
    pkA = srt4[min(wbase + (lane & 15), nE - 1)];
    cntA = min(wend - wbase, 16);
    int s0 = __shfl((int)pkA, o) & 0xFFFFFF;
    int s1 = __shfl((int)pkA, 8 + o) & 0xFFFFFF;
    vA0 = *(const uint4*)(t1 + (size_t)((o < cntA) ? s0 : 0) * 64 + j8 * 8);
    vA1 = *(const uint4*)(t1 + (size_t)((8 + o < cntA) ? s1 : 0) * 64 + j8 * 8);
  }
  if (ng > 1) {
    int nb = wbase + 16;
    pkB = srt4[min(nb + (lane & 15), nE - 1)];
    cntB = min(wend - nb, 16);
    int s0 = __shfl((int)pkB, o) & 0xFFFFFF;
    int s1 = __shfl((int)pkB, 8 + o) & 0xFFFFFF;
    vB0 = *(const uint4*)(t1 + (size_t)((o < cntB) ? s0 : 0) * 64 + j8 * 8);
    vB1 = *(const uint4*)(t1 + (size_t)((8 + o < cntB) ? s1 : 0) * 64 + j8 * 8);
  }

  for (int gg = 0; gg < ng; gg += 2) {
    bool hasB = (gg + 1 < ng);
    *(uint4*)(stA + o * TROW + j8 * 8) = vA0;
    *(uint4*)(stA + (8 + o) * TROW + j8 * 8) = vA1;
    if (hasB) {
      *(uint4*)(stB + o * TROW + j8 * 8) = vB0;
      *(uint4*)(stB + (8 + o) * TROW + j8 * 8) = vB1;
    }
    unsigned amA[8], amB[8];
#pragma unroll
    for (int m = 0; m < 8; ++m) {
      int e = 8 * hi + m;
      int pv = __shfl((int)pkA, e);
      bool ok = (e < cntA) && (((pv >> 24) & 31) == l31);
      amA[m] = ok ? 0x3F80u : 0u;
      degc += (amA[m] >> 7) & 1;
    }
    if (hasB) {
#pragma unroll
      for (int m = 0; m < 8; ++m) {
        int e = 8 * hi + m;
        int pv = __shfl((int)pkB, e);
        bool ok = (e < cntB) && (((pv >> 24) & 31) == l31);
        amB[m] = ok ? 0x3F80u : 0u;
        degc += (amB[m] >> 7) & 1;
      }
    }
    if (gg + 2 < ng) {
      int nb = wbase + (gg + 2) * 16;
      pkA = srt4[min(nb + (lane & 15), nE - 1)];
      cntA = min(wend - nb, 16);
      int s0 = __shfl((int)pkA, o) & 0xFFFFFF;
      int s1 = __shfl((int)pkA, 8 + o) & 0xFFFFFF;
      vA0 = *(const uint4*)(t1 + (size_t)((o < cntA) ? s0 : 0) * 64 + j8 * 8);
      vA1 = *(const uint4*)(t1 + (size_t)((8 + o < cntA) ? s1 : 0) * 64 + j8 * 8);
    }
    if (gg + 3 < ng) {
      int nb = wbase + (gg + 3) * 16;
      pkB = srt4[min(nb + (lane & 15), nE - 1)];
      cntB = min(wend - nb, 16);
      int s0 = __shfl((int)pkB, o) & 0xFFFFFF;
      int s1 = __shfl((int)pkB, 8 + o) & 0xFFFFFF;
      vB0 = *(const uint4*)(t1 + (size_t)((o < cntB) ? s0 : 0) * 64 + j8 * 8);
      vB1 = *(const uint4*)(t1 + (size_t)((8 + o < cntB) ? s1 : 0) * 64 + j8 * 8);
    }
    {
      Pack8 I;
      I.u.x = amA[0] | (amA[1] << 16);
      I.u.y = amA[2] | (amA[3] << 16);
      I.u.z = amA[4] | (amA[5] << 16);
      I.u.w = amA[6] | (amA[7] << 16);
      unsigned short b0[8], b1[8];
#pragma unroll
      for (int m = 0; m < 8; ++m) {
        b0[m] = stA[(8 * hi + m) * TROW + l31];
        b1[m] = stA[(8 * hi + m) * TROW + 32 + l31];
      }
      Pack8 F0, F1;
      F0.u.x = b0[0] | ((unsigned)b0[1] << 16);
      F0.u.y = b0[2] | ((unsigned)b0[3] << 16);
      F0.u.z = b0[4] | ((unsigned)b0[5] << 16);
      F0.u.w = b0[6] | ((unsigned)b0[7] << 16);
      F1.u.x = b1[0] | ((unsigned)b1[1] << 16);
      F1.u.y = b1[2] | ((unsigned)b1[3] << 16);
      F1.u.z = b1[4] | ((unsigned)b1[5] << 16);
      F1.u.w = b1[6] | ((unsigned)b1[7] << 16);
      acc0 = __builtin_amdgcn_mfma_f32_32x32x16_bf16(F0.s, I.s, acc0, 0, 0, 0);
      acc1 = __builtin_amdgcn_mfma_f32_32x32x16_bf16(F1.s, I.s, acc1, 0, 0, 0);
    }
    if (hasB) {
      Pack8 I;
      I.u.x = amB[0] | (amB[1] << 16);
      I.u.y = amB[2] | (amB[3] << 16);
      I.u.z = amB[4] | (amB[5] << 16);
      I.u.w = amB[6] | (amB[7] << 16);
      unsigned short b0[8], b1[8];
#pragma unroll
      for (int m = 0; m < 8; ++m) {
        b0[m] = stB[(8 * hi + m) * TROW + l31];
        b1[m] = stB[(8 * hi + m) * TROW + 32 + l31];
      }
      Pack8 F0, F1;
      F0.u.x = b0[0] | ((unsigned)b0[1] << 16);
      F0.u.y = b0[2] | ((unsigned)b0[3] << 16);
      F0.u.z = b0[4] | ((unsigned)b0[5] << 16);
      F0.u.w = b0[6] | ((unsigned)b0[7] << 16);
      F1.u.x = b1[0] | ((unsigned)b1[1] << 16);
      F1.u.y = b1[2] | ((unsigned)b1[3] << 16);
      F1.u.z = b1[4] | ((unsigned)b1[5] << 16);
      F1.u.w = b1[6] | ((unsigned)b1[7] << 16);
      acc0 = __builtin_amdgcn_mfma_f32_32x32x16_bf16(F0.s, I.s, acc0, 0, 0, 0);
      acc1 = __builtin_amdgcn_mfma_f32_32x32x16_bf16(F1.s, I.s, acc1, 0, 0, 0);
    }
  }

  ideg[w][lane] = degc;
  __syncthreads();
  float* red = (float*)&stg[0][0][0];
  for (int r = 1; r < 4; ++r) {
    if (w == r) {
#pragma unroll
      for (int i = 0; i < 16; ++i) {
        red[i * 64 + lane] = acc0[i];
        red[(16 + i) * 64 + lane] = acc1[i];
      }
    }
    __syncthreads();
    if (w == 0) {
#pragma unroll
      for (int i = 0; i < 16; ++i) {
        acc0[i] += red[i * 64 + lane];
        acc1[i] += red[(16 + i) * 64 + lane];
      }
    }
    __syncthreads();
  }

  if (w == 0) {
    int dtot = ideg[0][lane] + ideg[1][lane] + ideg[2][lane] + ideg[3][lane];
    float degf = (float)(dtot + __shfl_xor(dtot, 32));
    float inv = 1.f / fmaxf(degf, 1.f);
    int node = tile * 32 + l31;
    float d0 = 0.f, d1 = 0.f, d2 = 0.f, d3 = 0.f;
#pragma unroll
    for (int fb = 0; fb < 2; ++fb) {
#pragma unroll
      for (int q4 = 0; q4 < 4; ++q4) {
        int f0 = fb * 32 + q4 * 8 + 4 * hi;
        uint2 rv = *(const uint2*)(r1b + (size_t)node * 64 + f0);
        float bias[4] = {BF_LO(rv.x), BF_HI(rv.x), BF_LO(rv.y), BF_HI(rv.y)};
#pragma unroll
        for (int j = 0; j < 4; ++j) {
          float a = fb ? acc1[q4 * 4 + j] : acc0[q4 * 4 + j];
          float hv = fmaxf(fmaf(a, inv, bias[j]), 0.f);
          int f = f0 + j;
          d0 = fmaf(hv, pAB[0][f], d0);
          d1 = fmaf(hv, pAB[1][f], d1);
          d2 = fmaf(hv, pAB[2][f], d2);
          d3 = fmaf(hv, pAB[3][f], d3);
        }
      }
    }
    d0 += __shfl_xor(d0, 32);
    d1 += __shfl_xor(d1, 32);
    d2 += __shfl_xor(d2, 32);
    d3 += __shfl_xor(d3, 32);
    if (hi == 0) {
      g2[node] = make_float2(d0, d1);
      s2[node] = make_float2(d2, d3);
    }
  }
}

// ---------- bucket_g2: per-bucket LDS accumulation of g2 -> out ----------
__global__ __launch_bounds__(256) void bucket_g2(
    const unsigned* __restrict__ pairs4, const int* __restrict__ bstart,
    const float2* __restrict__ g2, const float2* __restrict__ s2,
    const float* __restrict__ bfv, float* __restrict__ out, int nE) {
  __shared__ float o0[256], o1[256];
  __shared__ int cnt[256];
  int t = threadIdx.x, b = blockIdx.x;
  o0[t] = 0.f;
  o1[t] = 0.f;
  cnt[t] = 0;
  __syncthreads();
  int base = bstart[b];
  int end = bstart[b + 1];
  for (int p = base + t; p < end; p += 256) {
    unsigned pk = pairs4[p];
    float2 v = g2[pk & 0xFFFFFFu];
    int dl = pk >> 24;
    atomicAdd(&o0[dl], v.x);
    atomicAdd(&o1[dl], v.y);
    atomicAdd(&cnt[dl], 1);
  }
  __syncthreads();
  int node = b * 256 + t;
  if (node < N_NODES) {
    float inv = 1.f / (float)max(cnt[t], 1);
    float2 sv = s2[node];
    out[(size_t)node * 2 + 0] = fmaf(o0[t], inv, sv.x) + bfv[0];
    out[(size_t)node * 2 + 1] = fmaf(o1[t], inv, sv.y) + bfv[1];
  }
}

extern "C" void kernel_launch(void* const* d_in, const int* in_sizes, int n_in,
                              void* d_out, int out_size, void* d_ws,
                              size_t ws_size, hipStream_t stream) {
  const float* x   = (const float*)d_in[0];
  const int*   ei  = (const int*)d_in[1];
  const float* Wl1 = (const float*)d_in[2];
  const float* bl1 = (const float*)d_in[3];
  const float* Wr1 = (const float*)d_in[4];
  const float* Wl2 = (const float*)d_in[5];
  const float* bl2 = (const float*)d_in[6];
  const float* Wr2 = (const float*)d_in[7];
  const float* Wc  = (const float*)d_in[8];
  const float* bc  = (const float*)d_in[9];
  float* out = (float*)d_out;

  int nE = in_sizes[1] / 2;
  const int* src = ei;
  const int* dst = ei + nE;

  // Workspace (~37 MB): pairs4 u32[E] | srt4 u32[E] | t1 bf16[N*64] |
  // r1b bf16[N*64] | g2,s2 f2[N] | A2/B2/bf | wcat | tstart[NBUCK*8+2] |
  // goff[GCNT_N] | btot[NBUCK+1] | bstart[NBUCK+1]
  unsigned* pairs4 = (unsigned*)d_ws;
  unsigned* srt4 = pairs4 + nE;
  unsigned short* t1 = (unsigned short*)(srt4 + nE);
  unsigned short* r1b = t1 + (size_t)N_NODES * D;
  float2* g2 = (float2*)(r1b + (size_t)N_NODES * D);
  float2* s2 = g2 + N_NODES;
  float* A2 = (float*)(s2 + N_NODES);
  float* B2 = A2 + 128;
  float* bfv = B2 + 128;
  unsigned short* wcat = (unsigned short*)(bfv + 4);
  int* tstart = (int*)(wcat + 8192);
  int* goff = tstart + (NBUCK * 8 + 2);
  int* btot = goff + GCNT_N;
  int* bstart = btot + (NBUCK + 1);

  int ec = (nE + NBLK_A - 1) / NBLK_A;

  hipMemsetAsync(btot, 0, (NBUCK + 1) * sizeof(int), stream);
  passA_count<<<NBLK_A, 256, 0, stream>>>(dst, goff, btot, nE, ec);
  passC_prep<<<NBLK_A + 1, 256, 0, stream>>>(src, dst, goff, btot, bstart,
                                             pairs4, nE, ec, Wc, Wl2, Wr2,
                                             bl2, bc, Wl1, Wr1, A2, B2, bfv,
                                             wcat);
  passD_transform<<<NBUCK + TBLK, 256, 0, stream>>>(pairs4, bstart, tstart,
                                                    srt4, nE, x, wcat, bl1,
                                                    t1, r1b);
  tile_g1<<<NTILES, 256, 0, stream>>>(srt4, tstart, t1, r1b, A2, B2, g2, s2,
                                      nE);
  bucket_g2<<<NBUCK, 256, 0, stream>>>(pairs4, bstart, g2, s2, bfv, out, nE);
}

// Round 18
// 124.442 us; speedup vs baseline: 1.1046x; 1.1046x over previous
//
#include <hip/hip_runtime.h>

#define N_NODES 100000
#define D 64
#define NTILES 3125       // 32-node output tiles for tile_g1
#define NBUCK 391         // 256-node buckets: dst>>8
#define NBLK_A 256        // blocks in count/place passes
#define GCNT_N (NBUCK * NBLK_A)            // 100096
#define NCHUNK ((GCNT_N + 255) / 256)      // 391
#define NTILE_T (N_NODES / 32)             // transform tiles
#define TROW 72           // staged row stride in bf16 elems (144B)
#define TBLK 512          // transform blocks inside fused kernel

typedef __attribute__((ext_vector_type(8))) short short8;
typedef __attribute__((ext_vector_type(16))) float f32x16;
union Pack8 { uint4 u; short8 s; };

__device__ __forceinline__ unsigned f2bf(float f) {  // RNE float->bf16 bits
  unsigned u = __float_as_uint(f);
  return (u + 0x7fffu + ((u >> 16) & 1u)) >> 16;
}
#define BF_LO(u) __uint_as_float(((unsigned)(u)) << 16)
#define BF_HI(u) __uint_as_float(((unsigned)(u)) & 0xffff0000u)

// Packed edge record: bits 31..24 = dst&255 (bucket-local), bits 23..0 = src.

// ---------- counting-sort to 256-node buckets ----------

__global__ __launch_bounds__(256) void passA_count(const int* __restrict__ dst,
                                                   int* __restrict__ gcnt,
                                                   int nE, int ec) {
  __shared__ int cnt[NBUCK];
  int t = threadIdx.x, blk = blockIdx.x;
  for (int i = t; i < NBUCK; i += 256) cnt[i] = 0;
  __syncthreads();
  int e0 = blk * ec, e1 = min(e0 + ec, nE);
  for (int e = e0 + t; e < e1; e += 256) atomicAdd(&cnt[dst[e] >> 8], 1);
  __syncthreads();
  for (int b = t; b < NBUCK; b += 256) gcnt[b * NBLK_A + blk] = cnt[b];
}

__global__ void gscan_p1(const int* __restrict__ g, int* __restrict__ csum) {
  int t = threadIdx.x, b = blockIdx.x;
  int i = b * 256 + t;
  int v = (i < GCNT_N) ? g[i] : 0;
  for (int off = 32; off; off >>= 1) v += __shfl_down(v, off);
  __shared__ int ws4[4];
  if ((t & 63) == 0) ws4[t >> 6] = v;
  __syncthreads();
  if (t == 0) csum[b] = ws4[0] + ws4[1] + ws4[2] + ws4[3];
}

__global__ void gscan_p2(int* __restrict__ csum, int nB) {
  __shared__ int s[1024];
  int t = threadIdx.x;
  int orig = (t < nB) ? csum[t] : 0;
  s[t] = orig;
  __syncthreads();
  for (int off = 1; off < 1024; off <<= 1) {
    int v = (t >= off) ? s[t - off] : 0;
    __syncthreads();
    s[t] += v;
    __syncthreads();
  }
  if (t < nB) csum[t] = s[t] - orig;  // exclusive block offsets
}

__global__ void gscan_p3(int* __restrict__ g, const int* __restrict__ csum) {
  __shared__ int s[256];
  int t = threadIdx.x, b = blockIdx.x;
  int i = b * 256 + t;
  int d = (i < GCNT_N) ? g[i] : 0;
  s[t] = d;
  __syncthreads();
  for (int off = 1; off < 256; off <<= 1) {
    int v = (t >= off) ? s[t - off] : 0;
    __syncthreads();
    s[t] += v;
    __syncthreads();
  }
  if (i < GCNT_N) g[i] = s[t] - d + csum[b];  // exclusive
}

// ---------- passC (blocks 0..NBLK_A-1) + prep (block NBLK_A) fused ----------
__global__ __launch_bounds__(256) void passC_prep(
    const int* __restrict__ src, const int* __restrict__ dst,
    const int* __restrict__ S, unsigned* __restrict__ pairs4, int nE, int ec,
    const float* __restrict__ Wc, const float* __restrict__ Wl2,
    const float* __restrict__ Wr2, const float* __restrict__ bl2,
    const float* __restrict__ bc, const float* __restrict__ Wl1,
    const float* __restrict__ Wr1, float* __restrict__ A2,
    float* __restrict__ B2, float* __restrict__ bfv,
    unsigned short* __restrict__ wcat) {
  __shared__ int cur[NBUCK];
  int t = threadIdx.x, blk = blockIdx.x;
  if (blk < NBLK_A) {
    for (int b = t; b < NBUCK; b += 256) cur[b] = S[b * NBLK_A + blk];
    __syncthreads();
    int e0 = blk * ec, e1 = min(e0 + ec, nE);
    for (int e = e0 + t; e < e1; e += 256) {
      int d = dst[e];
      int p = atomicAdd(&cur[d >> 8], 1);
      pairs4[p] = ((unsigned)(d & 255) << 24) | (unsigned)src[e];
    }
  } else {
    for (int i = t; i < 8192; i += 256)
      wcat[i] = (unsigned short)f2bf((i < 4096) ? Wl1[i] : Wr1[i - 4096]);
    if (t < 128) {
      int c = t >> 6, k = t & 63;
      float sa = 0.f, sb = 0.f;
      for (int j = 0; j < 64; ++j) {
        float w = Wc[c * 64 + j];
        sa = fmaf(w, Wl2[j * 64 + k], sa);
        sb = fmaf(w, Wr2[j * 64 + k], sb);
      }
      A2[c * 64 + k] = sa;
      B2[c * 64 + k] = sb;
    }
    if (t < 2) {
      float s = bc[t];
      for (int j = 0; j < 64; ++j) s = fmaf(Wc[t * 64 + j], bl2[j], s);
      bfv[t] = s;
    }
  }
}

// ---------- fused: tile-sort passD (blocks 0..NBUCK-1) + transform ----------
__global__ __launch_bounds__(256) void passD_transform(
    const unsigned* __restrict__ pairs4, const int* __restrict__ S,
    int* __restrict__ tstart, unsigned* __restrict__ srt4, int nE,
    const float* __restrict__ x, const unsigned short* __restrict__ wcat,
    const float* __restrict__ bl, unsigned short* __restrict__ t1,
    unsigned short* __restrict__ r1b) {
  __shared__ int h8[8 * 16];
  __shared__ int ex8[9];
  __shared__ int cur8[8];
  int t = threadIdx.x;
  if (blockIdx.x < NBUCK) {
    int b = blockIdx.x;
    int base = S[b * NBLK_A];
    int end = (b == NBUCK - 1) ? nE : S[(b + 1) * NBLK_A];
    if (t < 128) h8[t] = 0;
    __syncthreads();
    for (int p = base + t; p < end; p += 256)
      atomicAdd(&h8[((pairs4[p] >> 29) & 7) * 16 + (t & 15)], 1);
    __syncthreads();
    if (t == 0) {
      int run = base;
      for (int bin = 0; bin < 8; ++bin) {
        ex8[bin] = run;
        int s = 0;
        for (int i = 0; i < 16; ++i) s += h8[bin * 16 + i];
        run += s;
      }
      ex8[8] = run;
    }
    __syncthreads();
    if (t < 8) {
      cur8[t] = ex8[t];
      tstart[b * 8 + t] = ex8[t];
    }
    if (b == NBUCK - 1 && t == 0) tstart[NBUCK * 8] = nE;
    __syncthreads();
    for (int p = base + t; p < end; p += 256) {
      unsigned pk = pairs4[p];
      int slot = atomicAdd(&cur8[(pk >> 29) & 7], 1);
      srt4[slot] = pk;
    }
  } else {
    int lane = t & 63;
    int l31 = lane & 31, hi = lane >> 5;

    short8 af[4][4];
#pragma unroll
    for (int jt = 0; jt < 4; ++jt)
#pragma unroll
      for (int kk = 0; kk < 4; ++kk)
        af[jt][kk] =
            *(const short8*)(wcat + (jt * 32 + l31) * 64 + kk * 16 + 8 * hi);

    const f32x16 Z = {0.f, 0.f, 0.f, 0.f, 0.f, 0.f, 0.f, 0.f,
                      0.f, 0.f, 0.f, 0.f, 0.f, 0.f, 0.f, 0.f};
    const float4* x4 = (const float4*)x;

    int gw = ((blockIdx.x - NBUCK) * 256 + t) >> 6;
    int nW = (TBLK * 256) >> 6;

    for (int tile = gw; tile < NTILE_T; tile += nW) {
      int node = tile * 32 + l31;
      f32x16 acc[4] = {Z, Z, Z, Z};
#pragma unroll
      for (int kk = 0; kk < 4; ++kk) {
        float4 fa = x4[(size_t)node * 16 + kk * 4 + 2 * hi];
        float4 fb = x4[(size_t)node * 16 + kk * 4 + 2 * hi + 1];
        Pack8 pk;
        pk.u.x = f2bf(fa.x) | (f2bf(fa.y) << 16);
        pk.u.y = f2bf(fa.z) | (f2bf(fa.w) << 16);
        pk.u.z = f2bf(fb.x) | (f2bf(fb.y) << 16);
        pk.u.w = f2bf(fb.z) | (f2bf(fb.w) << 16);
        acc[0] = __builtin_amdgcn_mfma_f32_32x32x16_bf16(af[0][kk], pk.s, acc[0], 0, 0, 0);
        acc[1] = __builtin_amdgcn_mfma_f32_32x32x16_bf16(af[1][kk], pk.s, acc[1], 0, 0, 0);
        acc[2] = __builtin_amdgcn_mfma_f32_32x32x16_bf16(af[2][kk], pk.s, acc[2], 0, 0, 0);
        acc[3] = __builtin_amdgcn_mfma_f32_32x32x16_bf16(af[3][kk], pk.s, acc[3], 0, 0, 0);
      }
#pragma unroll
      for (int jt = 0; jt < 2; ++jt)
#pragma unroll
        for (int rg = 0; rg < 4; ++rg) {
          int j0 = jt * 32 + 8 * rg + 4 * hi;
          uint2 p;
          p.x = f2bf(acc[jt][4 * rg + 0]) | (f2bf(acc[jt][4 * rg + 1]) << 16);
          p.y = f2bf(acc[jt][4 * rg + 2]) | (f2bf(acc[jt][4 * rg + 3]) << 16);
          *(uint2*)(t1 + (size_t)node * 64 + j0) = p;
        }
#pragma unroll
      for (int jt = 2; jt < 4; ++jt)
#pragma unroll
        for (int rg = 0; rg < 4; ++rg) {
          int j0 = (jt - 2) * 32 + 8 * rg + 4 * hi;
          float4 bv = ((const float4*)bl)[j0 >> 2];
          uint2 p;
          p.x = f2bf(acc[jt][4 * rg + 0] + bv.x) |
                (f2bf(acc[jt][4 * rg + 1] + bv.y) << 16);
          p.y = f2bf(acc[jt][4 * rg + 2] + bv.z) |
                (f2bf(acc[jt][4 * rg + 3] + bv.w) << 16);
          *(uint2*)(r1b + (size_t)node * 64 + j0) = p;
        }
    }
  }
}

// ---------- tile_g1: MFMA indicator-gather, 4 waves per tile ----------
__global__ __launch_bounds__(256) void tile_g1(
    const unsigned* __restrict__ srt4, const int* __restrict__ tstart,
    const unsigned short* __restrict__ t1,
    const unsigned short* __restrict__ r1b, const float* __restrict__ A2,
    const float* __restrict__ B2, float2* __restrict__ g2,
    float2* __restrict__ s2, int nE) {
  __shared__ float pAB[4][64];
  __shared__ unsigned short stg[4][2][16 * TROW];
  __shared__ int ideg[4][64];
  int t = threadIdx.x, lane = t & 63, w = t >> 6;
  pAB[t >> 6][t & 63] = (t < 128) ? A2[t] : B2[t - 128];
  __syncthreads();

  int tile = blockIdx.x;
  int base = tstart[tile];
  int end = tstart[tile + 1];
  int l31 = lane & 31, hi = lane >> 5;
  int o = lane >> 3, j8 = lane & 7;
  unsigned short* stA = &stg[w][0][0];
  unsigned short* stB = &stg[w][1][0];

  int ngAll = (end > base) ? ((end - base + 15) >> 4) : 0;
  int gper = (ngAll + 3) >> 2;
  int wbase = base + min(w * gper, ngAll) * 16;
  int wend = min(base + min((w + 1) * gper, ngAll) * 16, end);

  const f32x16 Z = {0.f, 0.f, 0.f, 0.f, 0.f, 0.f, 0.f, 0.f,
                    0.f, 0.f, 0.f, 0.f, 0.f, 0.f, 0.f, 0.f};
  f32x16 acc0 = Z, acc1 = Z;
  int degc = 0;
  int ng = (wend > wbase) ? ((wend - wbase + 15) >> 4) : 0;

  unsigned pkA = 0u, pkB = 0u;
  int cntA = 0, cntB = 0;
  uint4 vA0 = make_uint4(0, 0, 0, 0), vA1 = vA0, vB0 = vA0, vB1 = vA0;
  if (ng > 0) {
    pkA = srt4[min(wbase + (lane & 15), nE - 1)];
    cntA = min(wend - wbase, 16);
    int s0 = __shfl((int)pkA, o) & 0xFFFFFF;
    int s1 = __shfl((int)pkA, 8 + o) & 0xFFFFFF;
    vA0 = *(const uint4*)(t1 + (size_t)((o < cntA) ? s0 : 0) * 64 + j8 * 8);
    vA1 = *(const uint4*)(t1 + (size_t)((8 + o < cntA) ? s1 : 0) * 64 + j8 * 8);
  }
  if (ng > 1) {
    int nb = wbase + 16;
    pkB = srt4[min(nb + (lane & 15), nE - 1)];
    cntB = min(wend - nb, 16);
    int s0 = __shfl((int)pkB, o) & 0xFFFFFF;
    int s1 = __shfl((int)pkB, 8 + o) & 0xFFFFFF;
    vB0 = *(const uint4*)(t1 + (size_t)((o < cntB) ? s0 : 0) * 64 + j8 * 8);
    vB1 = *(const uint4*)(t1 + (size_t)((8 + o < cntB) ? s1 : 0) * 64 + j8 * 8);
  }

  for (int gg = 0; gg < ng; gg += 2) {
    bool hasB = (gg + 1 < ng);
    *(uint4*)(stA + o * TROW + j8 * 8) = vA0;
    *(uint4*)(stA + (8 + o) * TROW + j8 * 8) = vA1;
    if (hasB) {
      *(uint4*)(stB + o * TROW + j8 * 8) = vB0;
      *(uint4*)(stB + (8 + o) * TROW + j8 * 8) = vB1;
    }
    unsigned amA[8], amB[8];
#pragma unroll
    for (int m = 0; m < 8; ++m) {
      int e = 8 * hi + m;
      int pv = __shfl((int)pkA, e);
      bool ok = (e < cntA) && (((pv >> 24) & 31) == l31);
      amA[m] = ok ? 0x3F80u : 0u;
      degc += (amA[m] >> 7) & 1;
    }
    if (hasB) {
#pragma unroll
      for (int m = 0; m < 8; ++m) {
        int e = 8 * hi + m;
        int pv = __shfl((int)pkB, e);
        bool ok = (e < cntB) && (((pv >> 24) & 31) == l31);
        amB[m] = ok ? 0x3F80u : 0u;
        degc += (amB[m] >> 7) & 1;
      }
    }
    if (gg + 2 < ng) {
      int nb = wbase + (gg + 2) * 16;
      pkA = srt4[min(nb + (lane & 15), nE - 1)];
      cntA = min(wend - nb, 16);
      int s0 = __shfl((int)pkA, o) & 0xFFFFFF;
      int s1 = __shfl((int)pkA, 8 + o) & 0xFFFFFF;
      vA0 = *(const uint4*)(t1 + (size_t)((o < cntA) ? s0 : 0) * 64 + j8 * 8);
      vA1 = *(const uint4*)(t1 + (size_t)((8 + o < cntA) ? s1 : 0) * 64 + j8 * 8);
    }
    if (gg + 3 < ng) {
      int nb = wbase + (gg + 3) * 16;
      pkB = srt4[min(nb + (lane & 15), nE - 1)];
      cntB = min(wend - nb, 16);
      int s0 = __shfl((int)pkB, o) & 0xFFFFFF;
      int s1 = __shfl((int)pkB, 8 + o) & 0xFFFFFF;
      vB0 = *(const uint4*)(t1 + (size_t)((o < cntB) ? s0 : 0) * 64 + j8 * 8);
      vB1 = *(const uint4*)(t1 + (size_t)((8 + o < cntB) ? s1 : 0) * 64 + j8 * 8);
    }
    {
      Pack8 I;
      I.u.x = amA[0] | (amA[1] << 16);
      I.u.y = amA[2] | (amA[3] << 16);
      I.u.z = amA[4] | (amA[5] << 16);
      I.u.w = amA[6] | (amA[7] << 16);
      unsigned short b0[8], b1[8];
#pragma unroll
      for (int m = 0; m < 8; ++m) {
        b0[m] = stA[(8 * hi + m) * TROW + l31];
        b1[m] = stA[(8 * hi + m) * TROW + 32 + l31];
      }
      Pack8 F0, F1;
      F0.u.x = b0[0] | ((unsigned)b0[1] << 16);
      F0.u.y = b0[2] | ((unsigned)b0[3] << 16);
      F0.u.z = b0[4] | ((unsigned)b0[5] << 16);
      F0.u.w = b0[6] | ((unsigned)b0[7] << 16);
      F1.u.x = b1[0] | ((unsigned)b1[1] << 16);
      F1.u.y = b1[2] | ((unsigned)b1[3] << 16);
      F1.u.z = b1[4] | ((unsigned)b1[5] << 16);
      F1.u.w = b1[6] | ((unsigned)b1[7] << 16);
      acc0 = __builtin_amdgcn_mfma_f32_32x32x16_bf16(F0.s, I.s, acc0, 0, 0, 0);
      acc1 = __builtin_amdgcn_mfma_f32_32x32x16_bf16(F1.s, I.s, acc1, 0, 0, 0);
    }
    if (hasB) {
      Pack8 I;
      I.u.x = amB[0] | (amB[1] << 16);
      I.u.y = amB[2] | (amB[3] << 16);
      I.u.z = amB[4] | (amB[5] << 16);
      I.u.w = amB[6] | (amB[7] << 16);
      unsigned short b0[8], b1[8];
#pragma unroll
      for (int m = 0; m < 8; ++m) {
        b0[m] = stB[(8 * hi + m) * TROW + l31];
        b1[m] = stB[(8 * hi + m) * TROW + 32 + l31];
      }
      Pack8 F0, F1;
      F0.u.x = b0[0] | ((unsigned)b0[1] << 16);
      F0.u.y = b0[2] | ((unsigned)b0[3] << 16);
      F0.u.z = b0[4] | ((unsigned)b0[5] << 16);
      F0.u.w = b0[6] | ((unsigned)b0[7] << 16);
      F1.u.x = b1[0] | ((unsigned)b1[1] << 16);
      F1.u.y = b1[2] | ((unsigned)b1[3] << 16);
      F1.u.z = b1[4] | ((unsigned)b1[5] << 16);
      F1.u.w = b1[6] | ((unsigned)b1[7] << 16);
      acc0 = __builtin_amdgcn_mfma_f32_32x32x16_bf16(F0.s, I.s, acc0, 0, 0, 0);
      acc1 = __builtin_amdgcn_mfma_f32_32x32x16_bf16(F1.s, I.s, acc1, 0, 0, 0);
    }
  }

  ideg[w][lane] = degc;
  __syncthreads();
  float* red = (float*)&stg[0][0][0];
  for (int r = 1; r < 4; ++r) {
    if (w == r) {
#pragma unroll
      for (int i = 0; i < 16; ++i) {
        red[i * 64 + lane] = acc0[i];
        red[(16 + i) * 64 + lane] = acc1[i];
      }
    }
    __syncthreads();
    if (w == 0) {
#pragma unroll
      for (int i = 0; i < 16; ++i) {
        acc0[i] += red[i * 64 + lane];
        acc1[i] += red[(16 + i) * 64 + lane];
      }
    }
    __syncthreads();
  }

  if (w == 0) {
    int dtot = ideg[0][lane] + ideg[1][lane] + ideg[2][lane] + ideg[3][lane];
    float degf = (float)(dtot + __shfl_xor(dtot, 32));
    float inv = 1.f / fmaxf(degf, 1.f);
    int node = tile * 32 + l31;
    float d0 = 0.f, d1 = 0.f, d2 = 0.f, d3 = 0.f;
#pragma unroll
    for (int fb = 0; fb < 2; ++fb) {
#pragma unroll
      for (int q4 = 0; q4 < 4; ++q4) {
        int f0 = fb * 32 + q4 * 8 + 4 * hi;
        uint2 rv = *(const uint2*)(r1b + (size_t)node * 64 + f0);
        float bias[4] = {BF_LO(rv.x), BF_HI(rv.x), BF_LO(rv.y), BF_HI(rv.y)};
#pragma unroll
        for (int j = 0; j < 4; ++j) {
          float a = fb ? acc1[q4 * 4 + j] : acc0[q4 * 4 + j];
          float hv = fmaxf(fmaf(a, inv, bias[j]), 0.f);
          int f = f0 + j;
          d0 = fmaf(hv, pAB[0][f], d0);
          d1 = fmaf(hv, pAB[1][f], d1);
          d2 = fmaf(hv, pAB[2][f], d2);
          d3 = fmaf(hv, pAB[3][f], d3);
        }
      }
    }
    d0 += __shfl_xor(d0, 32);
    d1 += __shfl_xor(d1, 32);
    d2 += __shfl_xor(d2, 32);
    d3 += __shfl_xor(d3, 32);
    if (hi == 0) {
      g2[node] = make_float2(d0, d1);
      s2[node] = make_float2(d2, d3);
    }
  }
}

// ---------- bucket_g2: per-bucket LDS accumulation of g2 -> out ----------
__global__ __launch_bounds__(256) void bucket_g2(
    const unsigned* __restrict__ pairs4, const int* __restrict__ S,
    const float2* __restrict__ g2, const float2* __restrict__ s2,
    const float* __restrict__ bfv, float* __restrict__ out, int nE) {
  __shared__ float o0[256], o1[256];
  __shared__ int cnt[256];
  int t = threadIdx.x, b = blockIdx.x;
  o0[t] = 0.f;
  o1[t] = 0.f;
  cnt[t] = 0;
  __syncthreads();
  int base = S[b * NBLK_A];
  int end = (b == NBUCK - 1) ? nE : S[(b + 1) * NBLK_A];
  for (int p = base + t; p < end; p += 256) {
    unsigned pk = pairs4[p];
    float2 v = g2[pk & 0xFFFFFFu];
    int dl = pk >> 24;
    atomicAdd(&o0[dl], v.x);
    atomicAdd(&o1[dl], v.y);
    atomicAdd(&cnt[dl], 1);
  }
  __syncthreads();
  int node = b * 256 + t;
  if (node < N_NODES) {
    float inv = 1.f / (float)max(cnt[t], 1);
    float2 sv = s2[node];
    out[(size_t)node * 2 + 0] = fmaf(o0[t], inv, sv.x) + bfv[0];
    out[(size_t)node * 2 + 1] = fmaf(o1[t], inv, sv.y) + bfv[1];
  }
}

extern "C" void kernel_launch(void* const* d_in, const int* in_sizes, int n_in,
                              void* d_out, int out_size, void* d_ws,
                              size_t ws_size, hipStream_t stream) {
  const float* x   = (const float*)d_in[0];
  const int*   ei  = (const int*)d_in[1];
  const float* Wl1 = (const float*)d_in[2];
  const float* bl1 = (const float*)d_in[3];
  const float* Wr1 = (const float*)d_in[4];
  const float* Wl2 = (const float*)d_in[5];
  const float* bl2 = (const float*)d_in[6];
  const float* Wr2 = (const float*)d_in[7];
  const float* Wc  = (const float*)d_in[8];
  const float* bc  = (const float*)d_in[9];
  float* out = (float*)d_out;

  int nE = in_sizes[1] / 2;
  const int* src = ei;
  const int* dst = ei + nE;

  // Workspace (~37 MB): pairs4 u32[E] | srt4 u32[E] | t1 bf16[N*64] |
  // r1b bf16[N*64] | g2,s2 f2[N] | A2/B2/bf | wcat | tstart[NBUCK*8+2] |
  // gcnt[100k] | csum[1024]
  unsigned* pairs4 = (unsigned*)d_ws;
  unsigned* srt4 = pairs4 + nE;
  unsigned short* t1 = (unsigned short*)(srt4 + nE);
  unsigned short* r1b = t1 + (size_t)N_NODES * D;
  float2* g2 = (float2*)(r1b + (size_t)N_NODES * D);
  float2* s2 = g2 + N_NODES;
  float* A2 = (float*)(s2 + N_NODES);
  float* B2 = A2 + 128;
  float* bfv = B2 + 128;
  unsigned short* wcat = (unsigned short*)(bfv + 4);
  int* tstart = (int*)(wcat + 8192);
  int* gcnt = tstart + (NBUCK * 8 + 2);
  int* csum = gcnt + GCNT_N;

  int ec = (nE + NBLK_A - 1) / NBLK_A;

  passA_count<<<NBLK_A, 256, 0, stream>>>(dst, gcnt, nE, ec);
  gscan_p1<<<NCHUNK, 256, 0, stream>>>(gcnt, csum);
  gscan_p2<<<1, 1024, 0, stream>>>(csum, NCHUNK);
  gscan_p3<<<NCHUNK, 256, 0, stream>>>(gcnt, csum);
  passC_prep<<<NBLK_A + 1, 256, 0, stream>>>(src, dst, gcnt, pairs4, nE, ec,
                                             Wc, Wl2, Wr2, bl2, bc, Wl1, Wr1,
                                             A2, B2, bfv, wcat);
  passD_transform<<<NBUCK + TBLK, 256, 0, stream>>>(pairs4, gcnt, tstart,
                                                    srt4, nE, x, wcat, bl1,
                                                    t1, r1b);
  tile_g1<<<NTILES, 256, 0, stream>>>(srt4, tstart, t1, r1b, A2, B2, g2, s2,
                                      nE);
  bucket_g2<<<NBUCK, 256, 0, stream>>>(pairs4, gcnt, g2, s2, bfv, out, nE);
}